// Round 7
// baseline (152.473 us; speedup 1.0000x reference)
//
#include <hip/hip_runtime.h>

#define BC 16
#define NN 2048
#define FF 128
#define DD 128
#define NEDGES 65536
#define NEG_INF -1e16f
#define LEAK 0.1f
#define CAPR 128   // per-row in-degree cap; P(Poisson(32) > 128) ~ 1e-35
#define THRS 20.0f // defer-max: exp(20)=4.9e8; scale cancels at normalize (verified R4/R5)

// bytes (each 0 or 1) -> 4-bit mask, byte0 -> bit0 (no carries: coefficients sum < 256 per byte)
__device__ __forceinline__ unsigned int nib4(unsigned int v) {
    return (((v & 0x01010101u) * 0x01020408u) >> 24) & 0xFu;
}

// ---------------- edge kernels ----------------
// byte-mask path: plain idempotent stores, zero atomics (duplicates just re-write 1)
__global__ void __launch_bounds__(256) edge_byte_kernel(const int* __restrict__ row,
                                                        const int* __restrict__ col,
                                                        unsigned char* __restrict__ m8) {
    const int e = blockIdx.x * 256 + threadIdx.x;
    m8[(size_t)row[e] * NN + (size_t)col[e]] = (unsigned char)1;
}

// fallback bit-mask path (verified R0-R6): device-scope atomicOr
__global__ void __launch_bounds__(256) edge_bit_kernel(const int* __restrict__ row,
                                                       const int* __restrict__ col,
                                                       unsigned int* __restrict__ mask) {
    const int e = blockIdx.x * 256 + threadIdx.x;
    const unsigned int key = (unsigned int)row[e] * NN + (unsigned int)col[e];
    atomicOr(&mask[key >> 5], 1u << (key & 31u));
}

// ---------------- zgemm: z = h @ W (standalone, unroll-2) ----------------
// one [32 x 128] tile of z per block; unroll-2 batches 8 global W loads +
// 8 LDS loads per backedge so L2 latency (~200cy) overlaps the 128 FMAs.
__global__ void __launch_bounds__(256) zgemm_kernel(const float* __restrict__ h,
                                                    const float* __restrict__ W,
                                                    float* __restrict__ z) {
    __shared__ float hs[32][FF];   // 16 KB
    const int tid = threadIdx.x;
    const size_t row0 = (size_t)blockIdx.x * 32;
    const float4* hv = (const float4*)(h + row0 * FF);
    float4* hsv = (float4*)&hs[0][0];
#pragma unroll
    for (int i = 0; i < 4; ++i) hsv[tid + 256 * i] = hv[tid + 256 * i];
    __syncthreads();

    const int c0 = (tid & 31) * 4;
    const int r0 = (tid >> 5) * 4;
    float acc[4][4] = {};
#pragma unroll 2
    for (int f = 0; f < FF; f += 4) {
        float4 a[4], bb[4];
#pragma unroll
        for (int r = 0; r < 4; ++r) a[r] = *(const float4*)&hs[r0 + r][f];
#pragma unroll
        for (int k = 0; k < 4; ++k) bb[k] = *(const float4*)&W[(f + k) * DD + c0];
#pragma unroll
        for (int r = 0; r < 4; ++r) {
            acc[r][0] += a[r].x * bb[0].x + a[r].y * bb[1].x + a[r].z * bb[2].x + a[r].w * bb[3].x;
            acc[r][1] += a[r].x * bb[0].y + a[r].y * bb[1].y + a[r].z * bb[2].y + a[r].w * bb[3].y;
            acc[r][2] += a[r].x * bb[0].z + a[r].y * bb[1].z + a[r].z * bb[2].z + a[r].w * bb[3].z;
            acc[r][3] += a[r].x * bb[0].w + a[r].y * bb[1].w + a[r].z * bb[2].w + a[r].w * bb[3].w;
        }
    }
#pragma unroll
    for (int r = 0; r < 4; ++r)
        *(float4*)&z[(row0 + r0 + r) * DD + c0] =
            make_float4(acc[r][0], acc[r][1], acc[r][2], acc[r][3]);
}

// ---------------- gat: fused decode + online softmax (R6-verified) -------
// BYTEM=1: mask is 4 MB of bytes; lane packs its 32 bytes into the same
// 32-bit word (bit k <-> col ln*32+k) the bit-mask path reads directly.
// Everything after `bits` is byte-identical to the R6-verified kernel.
template <int BYTEM>
__global__ void __launch_bounds__(256) gat_kernel(const float* __restrict__ z,
                                                  const unsigned int* __restrict__ mask,
                                                  float* __restrict__ out) {
    __shared__ unsigned short hits_l[4][CAPR];   // 1 KB, one row per wave
    const int tid = threadIdx.x, wv = tid >> 6, ln = tid & 63;
    const int blk = blockIdx.x;
    const int b = ((blk & 7) << 1) | (wv & 1);
    const int n = ((blk >> 3) << 1) | (wv >> 1);
    const int eq = ln >> 3, hq = ln & 7;

    // ---- build this lane's 32-col bit word
    unsigned int bits;
    if constexpr (BYTEM) {
        const unsigned int* mrow = mask + n * (NN / 4);    // 512 words/row
        const uint4 q0 = *(const uint4*)(mrow + ln * 8);
        const uint4 q1 = *(const uint4*)(mrow + ln * 8 + 4);
        bits = nib4(q0.x) | (nib4(q0.y) << 4) | (nib4(q0.z) << 8) | (nib4(q0.w) << 12)
             | (nib4(q1.x) << 16) | (nib4(q1.y) << 20) | (nib4(q1.z) << 24) | (nib4(q1.w) << 28);
    } else {
        bits = mask[n * 64 + ln];
    }

    // ---- in-wave CSR decode (wave-private LDS; same-wave DS ordering)
    const int cnt = __popc(bits);
    int pre = cnt;
#pragma unroll
    for (int off = 1; off <= 32; off <<= 1) {
        const int t = __shfl_up(pre, off, 64);
        if (ln >= off) pre += t;
    }
    const int total = __shfl(pre, 63, 64);   // inclusive total = row degree
    int slot = pre - cnt;                    // exclusive prefix = lane's base
    while (bits) {
        const int bit = __ffs(bits) - 1;
        bits &= bits - 1;
        if (slot < CAPR) hits_l[wv][slot] = (unsigned short)(ln * 32 + bit);
        ++slot;
    }
    const int nh = min(total, CAPR);
    // preload edge list to registers (slots >= total are uninit: masked below)
    const int hv0 = hits_l[wv][ln];          // edges 0..63
    const int hv1 = hits_l[wv][64 + ln];     // edges 64..127

    const float* zb = z + ((size_t)b << 18);   // b*2048*128
    const float4* znp = (const float4*)(zb + ((size_t)n << 7) + (hq << 4));
    const float4 a0 = znp[0], a1 = znp[1], a2 = znp[2], a3 = znp[3];

    float m = NEG_INF, l = 0.f;
    float4 acc0 = make_float4(0.f, 0.f, 0.f, 0.f), acc1 = acc0, acc2 = acc0, acc3 = acc0;

#pragma unroll 2
    for (int c0 = 0; c0 < nh; c0 += 8) {
        const int e = c0 + eq;
        const int hv = (c0 < 64) ? hv0 : hv1;      // uniform select (c0 loop-scalar)
        const int he = __shfl(hv, e & 63, 64) & (NN - 1);   // edge id from registers
        const float4* zc = (const float4*)(zb + ((size_t)he << 7) + (hq << 4));
        const float4 v0 = zc[0], v1 = zc[1], v2 = zc[2], v3 = zc[3];
        // two independent 8-FMA chains halve the serial dot depth
        float ch0 = a0.x * v0.x + a0.y * v0.y + a0.z * v0.z + a0.w * v0.w
                  + a1.x * v1.x + a1.y * v1.y + a1.z * v1.z + a1.w * v1.w;
        float ch1 = a2.x * v2.x + a2.y * v2.y + a2.z * v2.z + a2.w * v2.w
                  + a3.x * v3.x + a3.y * v3.y + a3.z * v3.z + a3.w * v3.w;
        float pt = ch0 + ch1;
        pt += __shfl_xor(pt, 1, 64);
        pt += __shfl_xor(pt, 2, 64);
        pt += __shfl_xor(pt, 4, 64);             // full 128-dim dot in all hq lanes
        float sv = pt > 0.f ? pt : LEAK * pt;    // leaky_relu(0.1)
        if (sv == 0.f || e >= nh) sv = NEG_INF;  // masked_fill(att==0) / pad

        if (__any(sv - m > THRS)) {              // defer-max rescale (rare)
            const float mnew = fmaxf(m, sv);
            const float alpha = __expf(m - mnew);
            m = mnew;
            l *= alpha;
            acc0.x *= alpha; acc0.y *= alpha; acc0.z *= alpha; acc0.w *= alpha;
            acc1.x *= alpha; acc1.y *= alpha; acc1.z *= alpha; acc1.w *= alpha;
            acc2.x *= alpha; acc2.y *= alpha; acc2.z *= alpha; acc2.w *= alpha;
            acc3.x *= alpha; acc3.y *= alpha; acc3.z *= alpha; acc3.w *= alpha;
        }
        const float pr = __expf(sv - m);         // exponent <= THRS, fp32-safe
        l += pr;
        acc0.x += pr * v0.x; acc0.y += pr * v0.y; acc0.z += pr * v0.z; acc0.w += pr * v0.w;
        acc1.x += pr * v1.x; acc1.y += pr * v1.y; acc1.z += pr * v1.z; acc1.w += pr * v1.w;
        acc2.x += pr * v2.x; acc2.y += pr * v2.y; acc2.z += pr * v2.z; acc2.w += pr * v2.w;
        acc3.x += pr * v3.x; acc3.y += pr * v3.y; acc3.z += pr * v3.z; acc3.w += pr * v3.w;
    }

    float M = m;
#pragma unroll
    for (int off = 8; off <= 32; off <<= 1) M = fmaxf(M, __shfl_xor(M, off, 64));

    if (nh > 0 && M > 0.5f * NEG_INF) {
        const float al = __expf(m - M);          // 0 for all-pad lanes
        l *= al;
        acc0.x *= al; acc0.y *= al; acc0.z *= al; acc0.w *= al;
        acc1.x *= al; acc1.y *= al; acc1.z *= al; acc1.w *= al;
        acc2.x *= al; acc2.y *= al; acc2.z *= al; acc2.w *= al;
        acc3.x *= al; acc3.y *= al; acc3.z *= al; acc3.w *= al;
#pragma unroll
        for (int off = 8; off <= 32; off <<= 1) {
            l += __shfl_xor(l, off, 64);
            acc0.x += __shfl_xor(acc0.x, off, 64); acc0.y += __shfl_xor(acc0.y, off, 64);
            acc0.z += __shfl_xor(acc0.z, off, 64); acc0.w += __shfl_xor(acc0.w, off, 64);
            acc1.x += __shfl_xor(acc1.x, off, 64); acc1.y += __shfl_xor(acc1.y, off, 64);
            acc1.z += __shfl_xor(acc1.z, off, 64); acc1.w += __shfl_xor(acc1.w, off, 64);
            acc2.x += __shfl_xor(acc2.x, off, 64); acc2.y += __shfl_xor(acc2.y, off, 64);
            acc2.z += __shfl_xor(acc2.z, off, 64); acc2.w += __shfl_xor(acc2.w, off, 64);
            acc3.x += __shfl_xor(acc3.x, off, 64); acc3.y += __shfl_xor(acc3.y, off, 64);
            acc3.z += __shfl_xor(acc3.z, off, 64); acc3.w += __shfl_xor(acc3.w, off, 64);
        }
        const float inv = 1.f / l;
        acc0.x *= inv; acc0.y *= inv; acc0.z *= inv; acc0.w *= inv;
        acc1.x *= inv; acc1.y *= inv; acc1.z *= inv; acc1.w *= inv;
        acc2.x *= inv; acc2.y *= inv; acc2.z *= inv; acc2.w *= inv;
        acc3.x *= inv; acc3.y *= inv; acc3.z *= inv; acc3.w *= inv;
    } else {
        // no valid edge: softmax over uniform -1e16 row -> mean of z[b]
        acc0 = make_float4(0.f, 0.f, 0.f, 0.f); acc1 = acc0; acc2 = acc0; acc3 = acc0;
        for (int mm = 0; mm < NN; ++mm) {
            const float4* zr = (const float4*)(zb + ((size_t)mm << 7) + (hq << 4));
            const float4 t0 = zr[0], t1 = zr[1], t2 = zr[2], t3 = zr[3];
            acc0.x += t0.x; acc0.y += t0.y; acc0.z += t0.z; acc0.w += t0.w;
            acc1.x += t1.x; acc1.y += t1.y; acc1.z += t1.z; acc1.w += t1.w;
            acc2.x += t2.x; acc2.y += t2.y; acc2.z += t2.z; acc2.w += t2.w;
            acc3.x += t3.x; acc3.y += t3.y; acc3.z += t3.z; acc3.w += t3.w;
        }
        const float s = 1.f / NN;
        acc0.x *= s; acc0.y *= s; acc0.z *= s; acc0.w *= s;
        acc1.x *= s; acc1.y *= s; acc1.z *= s; acc1.w *= s;
        acc2.x *= s; acc2.y *= s; acc2.z *= s; acc2.w *= s;
        acc3.x *= s; acc3.y *= s; acc3.z *= s; acc3.w *= s;
    }

    if (eq < 4) {
        float4 o = acc0;
        if (eq == 1) o = acc1;
        if (eq == 2) o = acc2;
        if (eq == 3) o = acc3;
        *(float4*)(out + (((size_t)b * NN + n) << 7) + (hq << 4) + (eq << 2)) = o;
    }
}

// ---------------- launcher ----------------
extern "C" void kernel_launch(void* const* d_in, const int* in_sizes, int n_in,
                              void* d_out, int out_size, void* d_ws, size_t ws_size,
                              hipStream_t stream) {
    const float* h = (const float*)d_in[0];
    const float* W = (const float*)d_in[1];
    const int* row = (const int*)d_in[2];
    const int* col = (const int*)d_in[3];
    float* out = (float*)d_out;

    char* ws = (char*)d_ws;
    float* z = (float*)ws;   // 16 MB

    if (ws_size >= (size_t)20 * 1024 * 1024 + 256) {
        // byte-mask path: no atomics anywhere
        unsigned char* m8 = (unsigned char*)(ws + (size_t)16 * 1024 * 1024);  // 4 MB
        hipMemsetAsync(m8, 0, (size_t)NN * NN, stream);
        edge_byte_kernel<<<NEDGES / 256, 256, 0, stream>>>(row, col, m8);
        zgemm_kernel<<<(BC * NN) / 32, 256, 0, stream>>>(h, W, z);
        gat_kernel<1><<<(BC * NN) / 4, 256, 0, stream>>>(z, (const unsigned int*)m8, out);
    } else {
        // fallback: verified bitmask + atomicOr path
        unsigned int* mask = (unsigned int*)(ws + (size_t)16 * 1024 * 1024);  // 512 KB
        hipMemsetAsync(mask, 0, (size_t)NN * NN / 8, stream);
        edge_bit_kernel<<<NEDGES / 256, 256, 0, stream>>>(row, col, mask);
        zgemm_kernel<<<(BC * NN) / 32, 256, 0, stream>>>(h, W, z);
        gat_kernel<0><<<(BC * NN) / 4, 256, 0, stream>>>(z, mask, out);
    }
}

// Round 8
// 142.910 us; speedup vs baseline: 1.0669x; 1.0669x over previous
//
#include <hip/hip_runtime.h>

#define BC 16
#define NN 2048
#define FF 128
#define DD 128
#define NEDGES 65536
#define NEG_INF -1e16f
#define LEAK 0.1f
#define CAPR 128   // per-row in-degree cap; P(Poisson(32) > 128) ~ 1e-35
#define THRS 20.0f // defer-max: exp(20)=4.9e8; scale cancels at normalize (verified R4/R5)

// ---------------- Kernel 1 (fused): edge atomicOr + z = h @ W ------------
// blocks 0..255: set adjacency bits (mask pre-zeroed by hipMemsetAsync);
// overlaps the GEMM blocks (verified harmless R0-R6, confirmed ~free by R7 split).
// blocks 256..1279: register-tiled zgemm, one [32 x 128] tile of z each.
// R8 change: W (64 KB) staged in LDS -> the f-loop is pure LDS+FMA, no
// global loads left in the loop (R7 showed the global-W f-loop ran at 13%
// of fp32 peak -- L2 latency-bound).
__global__ void __launch_bounds__(256) zedge_kernel(const float* __restrict__ h,
                                                    const float* __restrict__ W,
                                                    float* __restrict__ z,
                                                    const int* __restrict__ row,
                                                    const int* __restrict__ col,
                                                    unsigned int* __restrict__ mask) {
    __shared__ float W_lds[FF][DD];   // 64 KB
    __shared__ float hs[32][FF];      // 16 KB  (80 KB total -> 2 blocks/CU)
    const int tid = threadIdx.x;
    const int blk = blockIdx.x;

    if (blk < 256) {   // ---- edge part (no LDS use; whole block returns together)
        const int e = blk * 256 + tid;
        const unsigned int key = (unsigned int)row[e] * NN + (unsigned int)col[e];
        atomicOr(&mask[key >> 5], 1u << (key & 31u));
        return;
    }

    // ---- stage W (16 float4/thread) and the 32-row h tile (4 float4/thread)
    {
        const float4* wg = (const float4*)W;
        float4* wl = (float4*)&W_lds[0][0];
#pragma unroll
        for (int i = 0; i < 16; ++i) wl[tid + 256 * i] = wg[tid + 256 * i];
        const size_t row0 = (size_t)(blk - 256) * 32;
        const float4* hv = (const float4*)(h + row0 * FF);
        float4* hsv = (float4*)&hs[0][0];
#pragma unroll
        for (int i = 0; i < 4; ++i) hsv[tid + 256 * i] = hv[tid + 256 * i];
    }
    __syncthreads();

    const size_t row0 = (size_t)(blk - 256) * 32;
    const int c0 = (tid & 31) * 4;
    const int r0 = (tid >> 5) * 4;
    float acc[4][4] = {};
#pragma unroll 2
    for (int f = 0; f < FF; f += 4) {
        float4 a[4], bb[4];
#pragma unroll
        for (int r = 0; r < 4; ++r) a[r] = *(const float4*)&hs[r0 + r][f];
#pragma unroll
        for (int k = 0; k < 4; ++k) bb[k] = *(const float4*)&W_lds[f + k][c0];
#pragma unroll
        for (int r = 0; r < 4; ++r) {
            acc[r][0] += a[r].x * bb[0].x + a[r].y * bb[1].x + a[r].z * bb[2].x + a[r].w * bb[3].x;
            acc[r][1] += a[r].x * bb[0].y + a[r].y * bb[1].y + a[r].z * bb[2].y + a[r].w * bb[3].y;
            acc[r][2] += a[r].x * bb[0].z + a[r].y * bb[1].z + a[r].z * bb[2].z + a[r].w * bb[3].z;
            acc[r][3] += a[r].x * bb[0].w + a[r].y * bb[1].w + a[r].z * bb[2].w + a[r].w * bb[3].w;
        }
    }
#pragma unroll
    for (int r = 0; r < 4; ++r)
        *(float4*)&z[(row0 + r0 + r) * DD + c0] =
            make_float4(acc[r][0], acc[r][1], acc[r][2], acc[r][3]);
}

// ---------------- Kernel 2: gat with fused in-wave CSR decode ------------
// (byte-identical to the R6-verified 57.5 us kernel: bitmask decode)
__global__ void __launch_bounds__(256) gat_kernel(const float* __restrict__ z,
                                                  const unsigned int* __restrict__ mask,
                                                  float* __restrict__ out) {
    __shared__ unsigned short hits_l[4][CAPR];   // 1 KB, one row per wave
    const int tid = threadIdx.x, wv = tid >> 6, ln = tid & 63;
    const int blk = blockIdx.x;
    const int b = ((blk & 7) << 1) | (wv & 1);
    const int n = ((blk >> 3) << 1) | (wv >> 1);
    const int eq = ln >> 3, hq = ln & 7;

    // ---- in-wave CSR decode (wave-private LDS; same-wave DS ordering)
    unsigned int bits = mask[n * 64 + ln];
    const int cnt = __popc(bits);
    int pre = cnt;
#pragma unroll
    for (int off = 1; off <= 32; off <<= 1) {
        const int t = __shfl_up(pre, off, 64);
        if (ln >= off) pre += t;
    }
    const int total = __shfl(pre, 63, 64);   // inclusive total = row degree
    int slot = pre - cnt;                    // exclusive prefix = lane's base
    while (bits) {
        const int bit = __ffs(bits) - 1;
        bits &= bits - 1;
        if (slot < CAPR) hits_l[wv][slot] = (unsigned short)(ln * 32 + bit);
        ++slot;
    }
    const int nh = min(total, CAPR);
    // preload edge list to registers (slots >= total are uninit: masked below)
    const int hv0 = hits_l[wv][ln];          // edges 0..63
    const int hv1 = hits_l[wv][64 + ln];     // edges 64..127

    const float* zb = z + ((size_t)b << 18);   // b*2048*128
    const float4* znp = (const float4*)(zb + ((size_t)n << 7) + (hq << 4));
    const float4 a0 = znp[0], a1 = znp[1], a2 = znp[2], a3 = znp[3];

    float m = NEG_INF, l = 0.f;
    float4 acc0 = make_float4(0.f, 0.f, 0.f, 0.f), acc1 = acc0, acc2 = acc0, acc3 = acc0;

#pragma unroll 2
    for (int c0 = 0; c0 < nh; c0 += 8) {
        const int e = c0 + eq;
        const int hv = (c0 < 64) ? hv0 : hv1;      // uniform select (c0 loop-scalar)
        const int he = __shfl(hv, e & 63, 64) & (NN - 1);   // edge id from registers
        const float4* zc = (const float4*)(zb + ((size_t)he << 7) + (hq << 4));
        const float4 v0 = zc[0], v1 = zc[1], v2 = zc[2], v3 = zc[3];
        // two independent 8-FMA chains halve the serial dot depth
        float ch0 = a0.x * v0.x + a0.y * v0.y + a0.z * v0.z + a0.w * v0.w
                  + a1.x * v1.x + a1.y * v1.y + a1.z * v1.z + a1.w * v1.w;
        float ch1 = a2.x * v2.x + a2.y * v2.y + a2.z * v2.z + a2.w * v2.w
                  + a3.x * v3.x + a3.y * v3.y + a3.z * v3.z + a3.w * v3.w;
        float pt = ch0 + ch1;
        pt += __shfl_xor(pt, 1, 64);
        pt += __shfl_xor(pt, 2, 64);
        pt += __shfl_xor(pt, 4, 64);             // full 128-dim dot in all hq lanes
        float sv = pt > 0.f ? pt : LEAK * pt;    // leaky_relu(0.1)
        if (sv == 0.f || e >= nh) sv = NEG_INF;  // masked_fill(att==0) / pad

        if (__any(sv - m > THRS)) {              // defer-max rescale (rare)
            const float mnew = fmaxf(m, sv);
            const float alpha = __expf(m - mnew);
            m = mnew;
            l *= alpha;
            acc0.x *= alpha; acc0.y *= alpha; acc0.z *= alpha; acc0.w *= alpha;
            acc1.x *= alpha; acc1.y *= alpha; acc1.z *= alpha; acc1.w *= alpha;
            acc2.x *= alpha; acc2.y *= alpha; acc2.z *= alpha; acc2.w *= alpha;
            acc3.x *= alpha; acc3.y *= alpha; acc3.z *= alpha; acc3.w *= alpha;
        }
        const float pr = __expf(sv - m);         // exponent <= THRS, fp32-safe
        l += pr;
        acc0.x += pr * v0.x; acc0.y += pr * v0.y; acc0.z += pr * v0.z; acc0.w += pr * v0.w;
        acc1.x += pr * v1.x; acc1.y += pr * v1.y; acc1.z += pr * v1.z; acc1.w += pr * v1.w;
        acc2.x += pr * v2.x; acc2.y += pr * v2.y; acc2.z += pr * v2.z; acc2.w += pr * v2.w;
        acc3.x += pr * v3.x; acc3.y += pr * v3.y; acc3.z += pr * v3.z; acc3.w += pr * v3.w;
    }

    float M = m;
#pragma unroll
    for (int off = 8; off <= 32; off <<= 1) M = fmaxf(M, __shfl_xor(M, off, 64));

    if (nh > 0 && M > 0.5f * NEG_INF) {
        const float al = __expf(m - M);          // 0 for all-pad lanes
        l *= al;
        acc0.x *= al; acc0.y *= al; acc0.z *= al; acc0.w *= al;
        acc1.x *= al; acc1.y *= al; acc1.z *= al; acc1.w *= al;
        acc2.x *= al; acc2.y *= al; acc2.z *= al; acc2.w *= al;
        acc3.x *= al; acc3.y *= al; acc3.z *= al; acc3.w *= al;
#pragma unroll
        for (int off = 8; off <= 32; off <<= 1) {
            l += __shfl_xor(l, off, 64);
            acc0.x += __shfl_xor(acc0.x, off, 64); acc0.y += __shfl_xor(acc0.y, off, 64);
            acc0.z += __shfl_xor(acc0.z, off, 64); acc0.w += __shfl_xor(acc0.w, off, 64);
            acc1.x += __shfl_xor(acc1.x, off, 64); acc1.y += __shfl_xor(acc1.y, off, 64);
            acc1.z += __shfl_xor(acc1.z, off, 64); acc1.w += __shfl_xor(acc1.w, off, 64);
            acc2.x += __shfl_xor(acc2.x, off, 64); acc2.y += __shfl_xor(acc2.y, off, 64);
            acc2.z += __shfl_xor(acc2.z, off, 64); acc2.w += __shfl_xor(acc2.w, off, 64);
            acc3.x += __shfl_xor(acc3.x, off, 64); acc3.y += __shfl_xor(acc3.y, off, 64);
            acc3.z += __shfl_xor(acc3.z, off, 64); acc3.w += __shfl_xor(acc3.w, off, 64);
        }
        const float inv = 1.f / l;
        acc0.x *= inv; acc0.y *= inv; acc0.z *= inv; acc0.w *= inv;
        acc1.x *= inv; acc1.y *= inv; acc1.z *= inv; acc1.w *= inv;
        acc2.x *= inv; acc2.y *= inv; acc2.z *= inv; acc2.w *= inv;
        acc3.x *= inv; acc3.y *= inv; acc3.z *= inv; acc3.w *= inv;
    } else {
        // no valid edge: softmax over uniform -1e16 row -> mean of z[b]
        acc0 = make_float4(0.f, 0.f, 0.f, 0.f); acc1 = acc0; acc2 = acc0; acc3 = acc0;
        for (int mm = 0; mm < NN; ++mm) {
            const float4* zr = (const float4*)(zb + ((size_t)mm << 7) + (hq << 4));
            const float4 t0 = zr[0], t1 = zr[1], t2 = zr[2], t3 = zr[3];
            acc0.x += t0.x; acc0.y += t0.y; acc0.z += t0.z; acc0.w += t0.w;
            acc1.x += t1.x; acc1.y += t1.y; acc1.z += t1.z; acc1.w += t1.w;
            acc2.x += t2.x; acc2.y += t2.y; acc2.z += t2.z; acc2.w += t2.w;
            acc3.x += t3.x; acc3.y += t3.y; acc3.z += t3.z; acc3.w += t3.w;
        }
        const float s = 1.f / NN;
        acc0.x *= s; acc0.y *= s; acc0.z *= s; acc0.w *= s;
        acc1.x *= s; acc1.y *= s; acc1.z *= s; acc1.w *= s;
        acc2.x *= s; acc2.y *= s; acc2.z *= s; acc2.w *= s;
        acc3.x *= s; acc3.y *= s; acc3.z *= s; acc3.w *= s;
    }

    if (eq < 4) {
        float4 o = acc0;
        if (eq == 1) o = acc1;
        if (eq == 2) o = acc2;
        if (eq == 3) o = acc3;
        *(float4*)(out + (((size_t)b * NN + n) << 7) + (hq << 4) + (eq << 2)) = o;
    }
}

// ---------------- launcher ----------------
extern "C" void kernel_launch(void* const* d_in, const int* in_sizes, int n_in,
                              void* d_out, int out_size, void* d_ws, size_t ws_size,
                              hipStream_t stream) {
    const float* h = (const float*)d_in[0];
    const float* W = (const float*)d_in[1];
    const int* row = (const int*)d_in[2];
    const int* col = (const int*)d_in[3];
    float* out = (float*)d_out;

    char* ws = (char*)d_ws;
    float* z = (float*)ws;                                                 // 16 MB
    unsigned int* mask = (unsigned int*)(ws + (size_t)16 * 1024 * 1024);   // 512 KB

    hipMemsetAsync(mask, 0, (size_t)NN * NN / 8, stream);   // DMA, ~2 us
    zedge_kernel<<<1280, 256, 0, stream>>>(h, W, z, row, col, mask);
    gat_kernel<<<(BC * NN) / 4, 256, 0, stream>>>(z, mask, out);
}